// Round 7
// baseline (100.888 us; speedup 1.0000x reference)
//
#include <hip/hip_runtime.h>
#include <hip/hip_bf16.h>

#define SREF 2048
#define DHEAD 128
#define KVBLK 128
#define NTHREADS 256
#define NTILES (SREF / KVBLK)          /* 16 */
#define PSTR 72
#define QSCALE 0.12751743f   /* log2(e)/sqrt(128) */
#define THRLOG 8.0f          /* defer-max threshold, log2 domain */

typedef short bf16x8 __attribute__((ext_vector_type(8)));
typedef float f32x4 __attribute__((ext_vector_type(4)));
typedef float f32x16 __attribute__((ext_vector_type(16)));

typedef const __attribute__((address_space(1))) void* gas_t;
typedef __attribute__((address_space(3))) void* las_t;

__device__ __forceinline__ ushort f2bf(float x) {
    unsigned u = __builtin_bit_cast(unsigned, x);
    u += 0x7fffu + ((u >> 16) & 1u);
    return (ushort)(u >> 16);
}

__device__ __forceinline__ float fexp2(float x) {
#if __has_builtin(__builtin_amdgcn_exp2f)
    return __builtin_amdgcn_exp2f(x);
#else
    return exp2f(x);
#endif
}

__device__ __forceinline__ unsigned cvtpk(float lo, float hi) {
    unsigned r;
    asm("v_cvt_pk_bf16_f32 %0, %1, %2" : "=v"(r) : "v"(lo), "v"(hi));
    return r;
}

// ---------------- precompute: K -> bf16, V -> V^T bf16 (full-row layout) ----------------
__global__ __launch_bounds__(NTHREADS) void preconv_kernel(
    const float* __restrict__ K, const float* __restrict__ V,
    ushort* __restrict__ Kb, ushort* __restrict__ VTb)
{
    __shared__ ushort T[DHEAD * PSTR];
    const int t  = threadIdx.x;
    const int bh = blockIdx.y;
    const int s0 = blockIdx.x * 64;
    const size_t base = (size_t)bh * SREF * DHEAD;

    const float* kb = K + base + (size_t)s0 * DHEAD;
    ushort* kout = Kb + base + (size_t)s0 * DHEAD;
    #pragma unroll
    for (int i = 0; i < 8; ++i) {
        int idx = t + i * NTHREADS;
        float4 f = *(const float4*)(kb + idx * 4);
        ushort4 h; h.x = f2bf(f.x); h.y = f2bf(f.y); h.z = f2bf(f.z); h.w = f2bf(f.w);
        *(ushort4*)(kout + idx * 4) = h;
    }

    const float* vb = V + base + (size_t)s0 * DHEAD;
    #pragma unroll
    for (int i = 0; i < 8; ++i) {
        const int key = (t & 31) + 32 * (i & 1);
        const int d4  = (t >> 5) + 8 * (i >> 1);
        float4 f = *(const float4*)(vb + key * DHEAD + d4 * 4);
        T[(d4 * 4 + 0) * PSTR + key] = f2bf(f.x);
        T[(d4 * 4 + 1) * PSTR + key] = f2bf(f.y);
        T[(d4 * 4 + 2) * PSTR + key] = f2bf(f.z);
        T[(d4 * 4 + 3) * PSTR + key] = f2bf(f.w);
    }
    __syncthreads();

    ushort* vt = VTb + (size_t)bh * DHEAD * SREF + s0;
    #pragma unroll
    for (int i = 0; i < 4; ++i) {
        int idx = t + i * NTHREADS;
        int d = idx >> 3;
        int c = (idx & 7) * 8;
        bf16x8 v = *(const bf16x8*)&T[d * PSTR + c];
        *(bf16x8*)(vt + (size_t)d * SREF + c) = v;
    }
}

// ---------------- main attention: 4 waves x 32 q-rows, 32x32 MFMA, KVBLK=128 ----------------
// LDS 64KB: Kbuf @0 (32KB, [128 keys][256B rows]); Vbuf @32768 (32KB, [128 d][256B rows]).
// 4-bit both-sides XOR swizzle ((row&15)<<4): 32 reading lanes spread over 16 slots
// -> 2-way bank aliasing (free, m136), vs 3-bit's residual 4-way.
// Single-buffered, 3-barrier schedule per phase:
//   vmcnt(8)+barA : K(t) staged & visible (V(t) may still be in flight)
//   QK(t)
//   vmcnt(0)+barB : own V(t) drained -> V visible; all QK done -> Kbuf free
//   STAGE_K(t+1)  : latency hidden under softmax+PV
//   softmax; PV(t)
//   barC          : all PV done -> Vbuf free
//   STAGE_V(t+1)  : latency hidden under next phase's QK
__global__ __launch_bounds__(NTHREADS, 2) void attn_fwd_kernel(
    const float* __restrict__ Q, const ushort* __restrict__ Kb,
    const ushort* __restrict__ VTb, float* __restrict__ O)
{
    __shared__ __align__(16) char smem[65536];

    const int t    = threadIdx.x;
    const int lane = t & 63;
    const int wv   = t >> 6;
    const int hi   = lane >> 5;
    const int q5   = lane & 31;
    const int sw   = (q5 & 15) << 4;   // 4-bit swizzle (rows of both tiles are 256B)

    const int bh = blockIdx.y;
    const int q0 = blockIdx.x * 128;
    const size_t base = (size_t)bh * SREF * DHEAD;

    // ---- Q B-fragments (log2-scaled) ----
    bf16x8 qf[8];
    {
        const float* qrow = Q + base + (size_t)(q0 + wv * 32 + q5) * DHEAD;
        #pragma unroll
        for (int dk = 0; dk < 8; ++dk) {
            const int d0 = dk * 16 + hi * 8;
            float4 a = *(const float4*)(qrow + d0);
            float4 b = *(const float4*)(qrow + d0 + 4);
            bf16x8 f;
            f[0] = (short)f2bf(a.x * QSCALE); f[1] = (short)f2bf(a.y * QSCALE);
            f[2] = (short)f2bf(a.z * QSCALE); f[3] = (short)f2bf(a.w * QSCALE);
            f[4] = (short)f2bf(b.x * QSCALE); f[5] = (short)f2bf(b.y * QSCALE);
            f[6] = (short)f2bf(b.z * QSCALE); f[7] = (short)f2bf(b.w * QSCALE);
            qf[dk] = f;
        }
    }

    const char* ksrcb = (const char*)(Kb + base);
    const char* vsrcb = (const char*)(VTb + (size_t)bh * DHEAD * SREF);

    const int kbaseL = q5 * 256 + ((hi * 16) ^ sw);   // K row = key (256B)

// K tile tt is 32KB contiguous in Kb; 4-bit pre-swizzled source, linear LDS dest
#define STAGE_K(tt) do {                                                        \
    const char* kt_ = ksrcb + (size_t)(tt) * 32768;                             \
    _Pragma("unroll")                                                           \
    for (int i_ = 0; i_ < 8; ++i_) {                                            \
        int L_ = t * 16 + i_ * 4096;                                            \
        int r_ = L_ >> 8;                                                       \
        __builtin_amdgcn_global_load_lds(                                       \
            (gas_t)(const void*)(kt_ + (L_ ^ ((r_ & 15) << 4))),                \
            (las_t)(void*)(smem + L_), 16, 0, 0);                               \
    }                                                                           \
} while (0)

// V^T rows are SREF-strided in VTb; tile tt columns start at byte tt*256
#define STAGE_V(tt) do {                                                        \
    const char* vt_ = vsrcb + (size_t)(tt) * 256;                               \
    _Pragma("unroll")                                                           \
    for (int i_ = 0; i_ < 8; ++i_) {                                            \
        int L_ = t * 16 + i_ * 4096;                                            \
        int d_ = L_ >> 8;                                                       \
        int c_ = L_ & 255;                                                      \
        __builtin_amdgcn_global_load_lds(                                       \
            (gas_t)(const void*)(vt_ + (size_t)d_ * (SREF * 2) + (c_ ^ ((d_ & 15) << 4))), \
            (las_t)(void*)(smem + 32768 + L_), 16, 0, 0);                       \
    }                                                                           \
} while (0)

    float mrun = -1e30f, lsumh = 0.0f;
    f32x16 acc[4];
    #pragma unroll
    for (int db = 0; db < 4; ++db)
        #pragma unroll
        for (int i = 0; i < 16; ++i) acc[db][i] = 0.0f;

    STAGE_K(0);
    STAGE_V(0);

    for (int tt = 0; tt < NTILES; ++tt) {
        asm volatile("s_waitcnt vmcnt(8)" ::: "memory");   // K(tt) done (V(tt) may fly)
        __builtin_amdgcn_s_barrier();
        __builtin_amdgcn_sched_barrier(0);

        // ---- S^T = K Q^T : 32 MFMAs, 4 independent chains ----
        f32x16 s0, s1, s2, s3;
        #pragma unroll
        for (int i = 0; i < 16; ++i) { s0[i] = 0.f; s1[i] = 0.f; s2[i] = 0.f; s3[i] = 0.f; }
        __builtin_amdgcn_s_setprio(1);
        #pragma unroll
        for (int dk = 0; dk < 8; ++dk) {
            const int off = kbaseL ^ (dk << 5);
            bf16x8 kf0 = *(const bf16x8*)(smem + off);
            s0 = __builtin_amdgcn_mfma_f32_32x32x16_bf16(kf0, qf[dk], s0, 0, 0, 0);
            bf16x8 kf1 = *(const bf16x8*)(smem + 8192 + off);
            s1 = __builtin_amdgcn_mfma_f32_32x32x16_bf16(kf1, qf[dk], s1, 0, 0, 0);
            bf16x8 kf2 = *(const bf16x8*)(smem + 16384 + off);
            s2 = __builtin_amdgcn_mfma_f32_32x32x16_bf16(kf2, qf[dk], s2, 0, 0, 0);
            bf16x8 kf3 = *(const bf16x8*)(smem + 24576 + off);
            s3 = __builtin_amdgcn_mfma_f32_32x32x16_bf16(kf3, qf[dk], s3, 0, 0, 0);
        }
        __builtin_amdgcn_s_setprio(0);

        asm volatile("s_waitcnt vmcnt(0)" ::: "memory");   // own V(tt) drained
        __builtin_amdgcn_s_barrier();                       // barB: V visible, Kbuf free
        __builtin_amdgcn_sched_barrier(0);
        if (tt + 1 < NTILES) STAGE_K(tt + 1);               // hidden under softmax+PV

        // ---- online softmax over 64 scores (base-2), two-half processing ----
        float m0[16];
        #pragma unroll
        for (int i = 0; i < 16; ++i)
            m0[i] = fmaxf(fmaxf(s0[i], s1[i]), fmaxf(s2[i], s3[i]));
        float m1[8];
        #pragma unroll
        for (int i = 0; i < 8; ++i) m1[i] = fmaxf(m0[i], m0[i + 8]);
        float pmax = fmaxf(fmaxf(fmaxf(m1[0], m1[1]), fmaxf(m1[2], m1[3])),
                           fmaxf(fmaxf(m1[4], m1[5]), fmaxf(m1[6], m1[7])));
        pmax = fmaxf(pmax, __shfl_xor(pmax, 32));

        if (!__all(pmax <= mrun + THRLOG)) {        // defer-max (T13)
            const float mnew  = fmaxf(mrun, pmax);
            const float alpha = fexp2(mrun - mnew);
            mrun = mnew;
            lsumh *= alpha;
            #pragma unroll
            for (int db = 0; db < 4; ++db)
                #pragma unroll
                for (int i = 0; i < 16; ++i) acc[db][i] *= alpha;
        }

        bf16x8 pa[8];
        float r0 = 0.f, r1 = 0.f, r2 = 0.f, r3 = 0.f;
        // half A: s0,s1 -> pa[0..3]
        #pragma unroll
        for (int i = 0; i < 16; i += 4) {
            s0[i]   = fexp2(s0[i]   - mrun); r0 += s0[i];
            s0[i+1] = fexp2(s0[i+1] - mrun); r1 += s0[i+1];
            s0[i+2] = fexp2(s0[i+2] - mrun); r2 += s0[i+2];
            s0[i+3] = fexp2(s0[i+3] - mrun); r3 += s0[i+3];
        }
        #pragma unroll
        for (int i = 0; i < 16; i += 4) {
            s1[i]   = fexp2(s1[i]   - mrun); r0 += s1[i];
            s1[i+1] = fexp2(s1[i+1] - mrun); r1 += s1[i+1];
            s1[i+2] = fexp2(s1[i+2] - mrun); r2 += s1[i+2];
            s1[i+3] = fexp2(s1[i+3] - mrun); r3 += s1[i+3];
        }
        #pragma unroll
        for (int kb = 0; kb < 2; ++kb) {
            #pragma unroll
            for (int c = 0; c < 2; ++c) {
                unsigned x0, x1, y0, y1;
                if (kb == 0) {
                    x0 = cvtpk(s0[8*c+0], s0[8*c+1]); x1 = cvtpk(s0[8*c+2], s0[8*c+3]);
                    y0 = cvtpk(s0[8*c+4], s0[8*c+5]); y1 = cvtpk(s0[8*c+6], s0[8*c+7]);
                } else {
                    x0 = cvtpk(s1[8*c+0], s1[8*c+1]); x1 = cvtpk(s1[8*c+2], s1[8*c+3]);
                    y0 = cvtpk(s1[8*c+4], s1[8*c+5]); y1 = cvtpk(s1[8*c+6], s1[8*c+7]);
                }
                asm volatile("v_permlane32_swap_b32 %0, %1" : "+v"(x0), "+v"(y0));
                asm volatile("v_permlane32_swap_b32 %0, %1" : "+v"(x1), "+v"(y1));
                union { unsigned u[4]; bf16x8 v; } U;
                U.u[0] = x0; U.u[1] = x1; U.u[2] = y0; U.u[3] = y1;
                pa[kb * 2 + c] = U.v;
            }
        }
        // half B: s2,s3 -> pa[4..7]
        #pragma unroll
        for (int i = 0; i < 16; i += 4) {
            s2[i]   = fexp2(s2[i]   - mrun); r0 += s2[i];
            s2[i+1] = fexp2(s2[i+1] - mrun); r1 += s2[i+1];
            s2[i+2] = fexp2(s2[i+2] - mrun); r2 += s2[i+2];
            s2[i+3] = fexp2(s2[i+3] - mrun); r3 += s2[i+3];
        }
        #pragma unroll
        for (int i = 0; i < 16; i += 4) {
            s3[i]   = fexp2(s3[i]   - mrun); r0 += s3[i];
            s3[i+1] = fexp2(s3[i+1] - mrun); r1 += s3[i+1];
            s3[i+2] = fexp2(s3[i+2] - mrun); r2 += s3[i+2];
            s3[i+3] = fexp2(s3[i+3] - mrun); r3 += s3[i+3];
        }
        #pragma unroll
        for (int kb = 0; kb < 2; ++kb) {
            #pragma unroll
            for (int c = 0; c < 2; ++c) {
                unsigned x0, x1, y0, y1;
                if (kb == 0) {
                    x0 = cvtpk(s2[8*c+0], s2[8*c+1]); x1 = cvtpk(s2[8*c+2], s2[8*c+3]);
                    y0 = cvtpk(s2[8*c+4], s2[8*c+5]); y1 = cvtpk(s2[8*c+6], s2[8*c+7]);
                } else {
                    x0 = cvtpk(s3[8*c+0], s3[8*c+1]); x1 = cvtpk(s3[8*c+2], s3[8*c+3]);
                    y0 = cvtpk(s3[8*c+4], s3[8*c+5]); y1 = cvtpk(s3[8*c+6], s3[8*c+7]);
                }
                asm volatile("v_permlane32_swap_b32 %0, %1" : "+v"(x0), "+v"(y0));
                asm volatile("v_permlane32_swap_b32 %0, %1" : "+v"(x1), "+v"(y1));
                union { unsigned u[4]; bf16x8 v; } U;
                U.u[0] = x0; U.u[1] = x1; U.u[2] = y0; U.u[3] = y1;
                pa[4 + kb * 2 + c] = U.v;
            }
        }
        lsumh += (r0 + r1) + (r2 + r3);

        // ---- O^T += V^T P^T : 32 MFMAs, 4 chains ----
        __builtin_amdgcn_s_setprio(1);
        #pragma unroll
        for (int db = 0; db < 4; ++db) {
            const int vrow = (db * 32 + q5) * 256 + ((hi * 16) ^ sw);
            #pragma unroll
            for (int ks = 0; ks < 8; ++ks) {
                bf16x8 vf = *(const bf16x8*)(smem + 32768 + (vrow ^ (ks << 5)));
                acc[db] = __builtin_amdgcn_mfma_f32_32x32x16_bf16(vf, pa[ks], acc[db], 0, 0, 0);
            }
        }
        __builtin_amdgcn_s_setprio(0);
        __builtin_amdgcn_sched_barrier(0);

        if (tt + 1 < NTILES) {
            __builtin_amdgcn_s_barrier();      // barC: all PV done -> Vbuf free
            STAGE_V(tt + 1);                   // hidden under next phase's QK
        }
    }

    // ---- epilogue: O^T -> O via LDS transpose, 2 rounds ----
    __syncthreads();
    const float lsum = lsumh + __shfl_xor(lsumh, 32);
    const float inv  = 1.0f / lsum;

    #pragma unroll
    for (int round = 0; round < 2; ++round) {
        if ((wv >> 1) == round) {
            const int eb = (wv & 1) * 16896;
            #pragma unroll
            for (int db = 0; db < 4; ++db) {
                #pragma unroll
                for (int c = 0; c < 4; ++c) {
                    f32x4 v;
                    v[0] = acc[db][4*c+0] * inv;
                    v[1] = acc[db][4*c+1] * inv;
                    v[2] = acc[db][4*c+2] * inv;
                    v[3] = acc[db][4*c+3] * inv;
                    *(f32x4*)(smem + eb + q5 * 528 + db * 128 + c * 32 + hi * 16) = v;
                }
            }
            #pragma unroll
            for (int i = 0; i < 16; ++i) {
                const int flat  = lane + i * 64;
                const int row   = flat >> 5;
                const int chunk = flat & 31;
                f32x4 v = *(const f32x4*)(smem + eb + row * 528 + chunk * 16);
                *(f32x4*)(O + base + (size_t)(q0 + wv * 32 + row) * DHEAD + chunk * 4) = v;
            }
        }
        __syncthreads();
    }
#undef STAGE_K
#undef STAGE_V
}

// ---------------- fallback (known-correct; used only if ws too small) ----------------
__global__ __launch_bounds__(NTHREADS) void attn_fwd_fallback(
    const float* __restrict__ Q, const float* __restrict__ K,
    const float* __restrict__ V, float* __restrict__ O)
{
    __shared__ ushort Ksh[64 * 136];
    __shared__ ushort Vsh[DHEAD * 72];
    __shared__ ushort Psh[4][16 * PSTR];

    const int t    = threadIdx.x;
    const int lane = t & 63;
    const int wv   = t >> 6;
    const int lq   = lane & 15;
    const int kh   = lane >> 4;

    const int bh = blockIdx.y;
    const int q0 = blockIdx.x * 64;
    const size_t base = (size_t)bh * SREF * DHEAD;

    const float scale = 0.08838834764831845f;
    bf16x8 qf[4];
    {
        const float* qrow = Q + base + (size_t)(q0 + wv * 16 + lq) * DHEAD;
        #pragma unroll
        for (int kk = 0; kk < 4; ++kk) {
            const int d0 = kk * 32 + kh * 8;
            float4 a = *(const float4*)(qrow + d0);
            float4 b = *(const float4*)(qrow + d0 + 4);
            bf16x8 f;
            f[0] = (short)f2bf(a.x * scale); f[1] = (short)f2bf(a.y * scale);
            f[2] = (short)f2bf(a.z * scale); f[3] = (short)f2bf(a.w * scale);
            f[4] = (short)f2bf(b.x * scale); f[5] = (short)f2bf(b.y * scale);
            f[6] = (short)f2bf(b.z * scale); f[7] = (short)f2bf(b.w * scale);
            qf[kk] = f;
        }
    }

    float mrun[4], lrun[4];
    f32x4 acc_o[8];
    #pragma unroll
    for (int r = 0; r < 4; ++r) { mrun[r] = -1e30f; lrun[r] = 0.0f; }
    #pragma unroll
    for (int db = 0; db < 8; ++db) acc_o[db] = (f32x4){0.f, 0.f, 0.f, 0.f};

    for (int kv0 = 0; kv0 < SREF; kv0 += 64) {
        __syncthreads();
        const float* kbase = K + base + (size_t)kv0 * DHEAD;
        #pragma unroll
        for (int i = 0; i < 8; ++i) {
            const int idx = t + i * NTHREADS;
            const int row = idx >> 5;
            const int c4  = idx & 31;
            float4 f = *(const float4*)(kbase + row * DHEAD + c4 * 4);
            ushort4 h;
            h.x = f2bf(f.x); h.y = f2bf(f.y); h.z = f2bf(f.z); h.w = f2bf(f.w);
            *(ushort4*)&Ksh[row * 136 + c4 * 4] = h;
        }
        const float* vbase = V + base + (size_t)kv0 * DHEAD;
        #pragma unroll
        for (int i = 0; i < 8; ++i) {
            const int key = (t & 31) + 32 * (i & 1);
            const int d4  = (t >> 5) + 8 * (i >> 1);
            float4 f = *(const float4*)(vbase + key * DHEAD + d4 * 4);
            Vsh[(d4 * 4 + 0) * 72 + key] = f2bf(f.x);
            Vsh[(d4 * 4 + 1) * 72 + key] = f2bf(f.y);
            Vsh[(d4 * 4 + 2) * 72 + key] = f2bf(f.z);
            Vsh[(d4 * 4 + 3) * 72 + key] = f2bf(f.w);
        }
        __syncthreads();

        f32x4 accs[4];
        #pragma unroll
        for (int nb = 0; nb < 4; ++nb) accs[nb] = (f32x4){0.f, 0.f, 0.f, 0.f};
        #pragma unroll
        for (int kk = 0; kk < 4; ++kk) {
            #pragma unroll
            for (int nb = 0; nb < 4; ++nb) {
                bf16x8 kf = *(const bf16x8*)&Ksh[(nb * 16 + lq) * 136 + kk * 32 + kh * 8];
                accs[nb] = __builtin_amdgcn_mfma_f32_16x16x32_bf16(qf[kk], kf, accs[nb], 0, 0, 0);
            }
        }

        float ps[4][4];
        #pragma unroll
        for (int r = 0; r < 4; ++r) {
            float v = fmaxf(fmaxf(accs[0][r], accs[1][r]), fmaxf(accs[2][r], accs[3][r]));
            #pragma unroll
            for (int mk = 1; mk < 16; mk <<= 1) v = fmaxf(v, __shfl_xor(v, mk));
            const float mnew  = fmaxf(mrun[r], v);
            const float alpha = __expf(mrun[r] - mnew);
            mrun[r] = mnew;
            float rs = 0.0f;
            #pragma unroll
            for (int nb = 0; nb < 4; ++nb) {
                const float p = __expf(accs[nb][r] - mnew);
                ps[nb][r] = p;
                rs += p;
            }
            #pragma unroll
            for (int mk = 1; mk < 16; mk <<= 1) rs += __shfl_xor(rs, mk);
            lrun[r] = lrun[r] * alpha + rs;
            #pragma unroll
            for (int db = 0; db < 8; ++db) acc_o[db][r] *= alpha;
        }

        #pragma unroll
        for (int nb = 0; nb < 4; ++nb)
            #pragma unroll
            for (int r = 0; r < 4; ++r)
                Psh[wv][(kh * 4 + r) * PSTR + nb * 16 + lq] = f2bf(ps[nb][r]);

        #pragma unroll
        for (int ks = 0; ks < 2; ++ks) {
            bf16x8 pa = *(const bf16x8*)&Psh[wv][lq * PSTR + ks * 32 + kh * 8];
            #pragma unroll
            for (int db = 0; db < 8; ++db) {
                bf16x8 vf = *(const bf16x8*)&Vsh[(db * 16 + lq) * 72 + ks * 32 + kh * 8];
                acc_o[db] = __builtin_amdgcn_mfma_f32_16x16x32_bf16(pa, vf, acc_o[db], 0, 0, 0);
            }
        }
    }

    #pragma unroll
    for (int r = 0; r < 4; ++r) {
        const float inv = 1.0f / lrun[r];
        float* orow = O + base + (size_t)(q0 + wv * 16 + kh * 4 + r) * DHEAD;
        #pragma unroll
        for (int db = 0; db < 8; ++db)
            orow[db * 16 + lq] = acc_o[db][r] * inv;
    }
}

extern "C" void kernel_launch(void* const* d_in, const int* in_sizes, int n_in,
                              void* d_out, int out_size, void* d_ws, size_t ws_size,
                              hipStream_t stream) {
    const float* Q = (const float*)d_in[0];
    const float* K = (const float*)d_in[1];
    const float* V = (const float*)d_in[2];
    float* O = (float*)d_out;
    const int BH = in_sizes[0] / (SREF * DHEAD);
    const size_t nel = (size_t)BH * SREF * DHEAD;

    if (ws_size >= 2 * nel * sizeof(ushort)) {
        ushort* Kb  = (ushort*)d_ws;
        ushort* VTb = Kb + nel;
        preconv_kernel<<<dim3(SREF / 64, BH), NTHREADS, 0, stream>>>(K, V, Kb, VTb);
        attn_fwd_kernel<<<dim3(SREF / 128, BH), NTHREADS, 0, stream>>>(Q, Kb, VTb, O);
    } else {
        attn_fwd_fallback<<<dim3(SREF / 64, BH), NTHREADS, 0, stream>>>(Q, K, V, O);
    }
}

// Round 8
// 98.656 us; speedup vs baseline: 1.0226x; 1.0226x over previous
//
#include <hip/hip_runtime.h>
#include <hip/hip_bf16.h>

#define SREF 2048
#define DHEAD 128
#define KVBLK 128
#define NTHREADS 256
#define NTILES (SREF / KVBLK)          /* 16 */
#define PSTR 72
#define QSCALE 0.12751743f   /* log2(e)/sqrt(128) */
#define THRLOG 8.0f          /* defer-max threshold, log2 domain */

typedef short bf16x8 __attribute__((ext_vector_type(8)));
typedef float f32x4 __attribute__((ext_vector_type(4)));
typedef float f32x16 __attribute__((ext_vector_type(16)));

typedef const __attribute__((address_space(1))) void* gas_t;
typedef __attribute__((address_space(3))) void* las_t;

__device__ __forceinline__ ushort f2bf(float x) {
    unsigned u = __builtin_bit_cast(unsigned, x);
    u += 0x7fffu + ((u >> 16) & 1u);
    return (ushort)(u >> 16);
}

__device__ __forceinline__ float fexp2(float x) {
#if __has_builtin(__builtin_amdgcn_exp2f)
    return __builtin_amdgcn_exp2f(x);
#else
    return exp2f(x);
#endif
}

__device__ __forceinline__ unsigned cvtpk(float lo, float hi) {
    unsigned r;
    asm("v_cvt_pk_bf16_f32 %0, %1, %2" : "=v"(r) : "v"(lo), "v"(hi));
    return r;
}

// ---------------- precompute: K -> bf16, V -> V^T bf16 (full-row layout) ----------------
__global__ __launch_bounds__(NTHREADS) void preconv_kernel(
    const float* __restrict__ K, const float* __restrict__ V,
    ushort* __restrict__ Kb, ushort* __restrict__ VTb)
{
    __shared__ ushort T[DHEAD * PSTR];
    const int t  = threadIdx.x;
    const int bh = blockIdx.y;
    const int s0 = blockIdx.x * 64;
    const size_t base = (size_t)bh * SREF * DHEAD;

    const float* kb = K + base + (size_t)s0 * DHEAD;
    ushort* kout = Kb + base + (size_t)s0 * DHEAD;
    #pragma unroll
    for (int i = 0; i < 8; ++i) {
        int idx = t + i * NTHREADS;
        float4 f = *(const float4*)(kb + idx * 4);
        ushort4 h; h.x = f2bf(f.x); h.y = f2bf(f.y); h.z = f2bf(f.z); h.w = f2bf(f.w);
        *(ushort4*)(kout + idx * 4) = h;
    }

    const float* vb = V + base + (size_t)s0 * DHEAD;
    #pragma unroll
    for (int i = 0; i < 8; ++i) {
        const int key = (t & 31) + 32 * (i & 1);
        const int d4  = (t >> 5) + 8 * (i >> 1);
        float4 f = *(const float4*)(vb + key * DHEAD + d4 * 4);
        T[(d4 * 4 + 0) * PSTR + key] = f2bf(f.x);
        T[(d4 * 4 + 1) * PSTR + key] = f2bf(f.y);
        T[(d4 * 4 + 2) * PSTR + key] = f2bf(f.z);
        T[(d4 * 4 + 3) * PSTR + key] = f2bf(f.w);
    }
    __syncthreads();

    ushort* vt = VTb + (size_t)bh * DHEAD * SREF + s0;
    #pragma unroll
    for (int i = 0; i < 4; ++i) {
        int idx = t + i * NTHREADS;
        int d = idx >> 3;
        int c = (idx & 7) * 8;
        bf16x8 v = *(const bf16x8*)&T[d * PSTR + c];
        *(bf16x8*)(vt + (size_t)d * SREF + c) = v;
    }
}

// ---------------- main attention: 4 waves x 32 q-rows, 32x32 MFMA, KVBLK=128 ----------------
// Grid (BH, NQT): linear block id b = head + 32*qtile -> b%8 = head%8 -> all 16
// q-blocks of one head land on ONE XCD (T1). Each XCD serves 4 heads; per-phase L2
// working set 4x64KB, whole-head K/V (4MB) fits the XCD L2 -> K/V staged from L2,
// not HBM, so the 1-tile prefetch window suffices.
// LDS 64KB: Kbuf @0 (32KB, [128 keys][256B rows]); Vbuf @32768 (32KB, [128 d][256B rows]).
// 4-bit both-sides XOR swizzle ((row&15)<<4): bank-conflict-free (R7: counter = 0).
// Single-buffered, 3-barrier schedule per phase (R6).
__global__ __launch_bounds__(NTHREADS, 2) void attn_fwd_kernel(
    const float* __restrict__ Q, const ushort* __restrict__ Kb,
    const ushort* __restrict__ VTb, float* __restrict__ O)
{
    __shared__ __align__(16) char smem[65536];

    const int t    = threadIdx.x;
    const int lane = t & 63;
    const int wv   = t >> 6;
    const int hi   = lane >> 5;
    const int q5   = lane & 31;
    const int sw   = (q5 & 15) << 4;   // 4-bit swizzle (rows of both tiles are 256B)

    const int bh = blockIdx.x;          // head fastest -> XCD affinity
    const int q0 = blockIdx.y * 128;
    const size_t base = (size_t)bh * SREF * DHEAD;

    // ---- Q B-fragments (log2-scaled) ----
    bf16x8 qf[8];
    {
        const float* qrow = Q + base + (size_t)(q0 + wv * 32 + q5) * DHEAD;
        #pragma unroll
        for (int dk = 0; dk < 8; ++dk) {
            const int d0 = dk * 16 + hi * 8;
            float4 a = *(const float4*)(qrow + d0);
            float4 b = *(const float4*)(qrow + d0 + 4);
            bf16x8 f;
            f[0] = (short)f2bf(a.x * QSCALE); f[1] = (short)f2bf(a.y * QSCALE);
            f[2] = (short)f2bf(a.z * QSCALE); f[3] = (short)f2bf(a.w * QSCALE);
            f[4] = (short)f2bf(b.x * QSCALE); f[5] = (short)f2bf(b.y * QSCALE);
            f[6] = (short)f2bf(b.z * QSCALE); f[7] = (short)f2bf(b.w * QSCALE);
            qf[dk] = f;
        }
    }

    const char* ksrcb = (const char*)(Kb + base);
    const char* vsrcb = (const char*)(VTb + (size_t)bh * DHEAD * SREF);

    const int kbaseL = q5 * 256 + ((hi * 16) ^ sw);   // K row = key (256B)

// K tile tt is 32KB contiguous in Kb; 4-bit pre-swizzled source, linear LDS dest
#define STAGE_K(tt) do {                                                        \
    const char* kt_ = ksrcb + (size_t)(tt) * 32768;                             \
    _Pragma("unroll")                                                           \
    for (int i_ = 0; i_ < 8; ++i_) {                                            \
        int L_ = t * 16 + i_ * 4096;                                            \
        int r_ = L_ >> 8;                                                       \
        __builtin_amdgcn_global_load_lds(                                       \
            (gas_t)(const void*)(kt_ + (L_ ^ ((r_ & 15) << 4))),                \
            (las_t)(void*)(smem + L_), 16, 0, 0);                               \
    }                                                                           \
} while (0)

// V^T rows are SREF-strided in VTb; tile tt columns start at byte tt*256
#define STAGE_V(tt) do {                                                        \
    const char* vt_ = vsrcb + (size_t)(tt) * 256;                               \
    _Pragma("unroll")                                                           \
    for (int i_ = 0; i_ < 8; ++i_) {                                            \
        int L_ = t * 16 + i_ * 4096;                                            \
        int d_ = L_ >> 8;                                                       \
        int c_ = L_ & 255;                                                      \
        __builtin_amdgcn_global_load_lds(                                       \
            (gas_t)(const void*)(vt_ + (size_t)d_ * (SREF * 2) + (c_ ^ ((d_ & 15) << 4))), \
            (las_t)(void*)(smem + 32768 + L_), 16, 0, 0);                       \
    }                                                                           \
} while (0)

    float mrun = -1e30f, lsumh = 0.0f;
    f32x16 acc[4];
    #pragma unroll
    for (int db = 0; db < 4; ++db)
        #pragma unroll
        for (int i = 0; i < 16; ++i) acc[db][i] = 0.0f;

    STAGE_K(0);
    STAGE_V(0);

    for (int tt = 0; tt < NTILES; ++tt) {
        asm volatile("s_waitcnt vmcnt(8)" ::: "memory");   // K(tt) done (V(tt) may fly)
        __builtin_amdgcn_s_barrier();
        __builtin_amdgcn_sched_barrier(0);

        // ---- S^T = K Q^T : 32 MFMAs, 4 independent chains ----
        f32x16 s0, s1, s2, s3;
        #pragma unroll
        for (int i = 0; i < 16; ++i) { s0[i] = 0.f; s1[i] = 0.f; s2[i] = 0.f; s3[i] = 0.f; }
        __builtin_amdgcn_s_setprio(1);
        #pragma unroll
        for (int dk = 0; dk < 8; ++dk) {
            const int off = kbaseL ^ (dk << 5);
            bf16x8 kf0 = *(const bf16x8*)(smem + off);
            s0 = __builtin_amdgcn_mfma_f32_32x32x16_bf16(kf0, qf[dk], s0, 0, 0, 0);
            bf16x8 kf1 = *(const bf16x8*)(smem + 8192 + off);
            s1 = __builtin_amdgcn_mfma_f32_32x32x16_bf16(kf1, qf[dk], s1, 0, 0, 0);
            bf16x8 kf2 = *(const bf16x8*)(smem + 16384 + off);
            s2 = __builtin_amdgcn_mfma_f32_32x32x16_bf16(kf2, qf[dk], s2, 0, 0, 0);
            bf16x8 kf3 = *(const bf16x8*)(smem + 24576 + off);
            s3 = __builtin_amdgcn_mfma_f32_32x32x16_bf16(kf3, qf[dk], s3, 0, 0, 0);
        }
        __builtin_amdgcn_s_setprio(0);

        asm volatile("s_waitcnt vmcnt(0)" ::: "memory");   // own V(tt) drained
        __builtin_amdgcn_s_barrier();                       // barB: V visible, Kbuf free
        __builtin_amdgcn_sched_barrier(0);
        if (tt + 1 < NTILES) STAGE_K(tt + 1);               // hidden under softmax+PV

        // ---- online softmax over 64 scores (base-2), two-half processing ----
        float m0[16];
        #pragma unroll
        for (int i = 0; i < 16; ++i)
            m0[i] = fmaxf(fmaxf(s0[i], s1[i]), fmaxf(s2[i], s3[i]));
        float m1[8];
        #pragma unroll
        for (int i = 0; i < 8; ++i) m1[i] = fmaxf(m0[i], m0[i + 8]);
        float pmax = fmaxf(fmaxf(fmaxf(m1[0], m1[1]), fmaxf(m1[2], m1[3])),
                           fmaxf(fmaxf(m1[4], m1[5]), fmaxf(m1[6], m1[7])));
        pmax = fmaxf(pmax, __shfl_xor(pmax, 32));

        if (!__all(pmax <= mrun + THRLOG)) {        // defer-max (T13)
            const float mnew  = fmaxf(mrun, pmax);
            const float alpha = fexp2(mrun - mnew);
            mrun = mnew;
            lsumh *= alpha;
            #pragma unroll
            for (int db = 0; db < 4; ++db)
                #pragma unroll
                for (int i = 0; i < 16; ++i) acc[db][i] *= alpha;
        }

        bf16x8 pa[8];
        float r0 = 0.f, r1 = 0.f, r2 = 0.f, r3 = 0.f;
        // half A: s0,s1 -> pa[0..3]
        #pragma unroll
        for (int i = 0; i < 16; i += 4) {
            s0[i]   = fexp2(s0[i]   - mrun); r0 += s0[i];
            s0[i+1] = fexp2(s0[i+1] - mrun); r1 += s0[i+1];
            s0[i+2] = fexp2(s0[i+2] - mrun); r2 += s0[i+2];
            s0[i+3] = fexp2(s0[i+3] - mrun); r3 += s0[i+3];
        }
        #pragma unroll
        for (int i = 0; i < 16; i += 4) {
            s1[i]   = fexp2(s1[i]   - mrun); r0 += s1[i];
            s1[i+1] = fexp2(s1[i+1] - mrun); r1 += s1[i+1];
            s1[i+2] = fexp2(s1[i+2] - mrun); r2 += s1[i+2];
            s1[i+3] = fexp2(s1[i+3] - mrun); r3 += s1[i+3];
        }
        #pragma unroll
        for (int kb = 0; kb < 2; ++kb) {
            #pragma unroll
            for (int c = 0; c < 2; ++c) {
                unsigned x0, x1, y0, y1;
                if (kb == 0) {
                    x0 = cvtpk(s0[8*c+0], s0[8*c+1]); x1 = cvtpk(s0[8*c+2], s0[8*c+3]);
                    y0 = cvtpk(s0[8*c+4], s0[8*c+5]); y1 = cvtpk(s0[8*c+6], s0[8*c+7]);
                } else {
                    x0 = cvtpk(s1[8*c+0], s1[8*c+1]); x1 = cvtpk(s1[8*c+2], s1[8*c+3]);
                    y0 = cvtpk(s1[8*c+4], s1[8*c+5]); y1 = cvtpk(s1[8*c+6], s1[8*c+7]);
                }
                asm volatile("v_permlane32_swap_b32 %0, %1" : "+v"(x0), "+v"(y0));
                asm volatile("v_permlane32_swap_b32 %0, %1" : "+v"(x1), "+v"(y1));
                union { unsigned u[4]; bf16x8 v; } U;
                U.u[0] = x0; U.u[1] = x1; U.u[2] = y0; U.u[3] = y1;
                pa[kb * 2 + c] = U.v;
            }
        }
        // half B: s2,s3 -> pa[4..7]
        #pragma unroll
        for (int i = 0; i < 16; i += 4) {
            s2[i]   = fexp2(s2[i]   - mrun); r0 += s2[i];
            s2[i+1] = fexp2(s2[i+1] - mrun); r1 += s2[i+1];
            s2[i+2] = fexp2(s2[i+2] - mrun); r2 += s2[i+2];
            s2[i+3] = fexp2(s2[i+3] - mrun); r3 += s2[i+3];
        }
        #pragma unroll
        for (int i = 0; i < 16; i += 4) {
            s3[i]   = fexp2(s3[i]   - mrun); r0 += s3[i];
            s3[i+1] = fexp2(s3[i+1] - mrun); r1 += s3[i+1];
            s3[i+2] = fexp2(s3[i+2] - mrun); r2 += s3[i+2];
            s3[i+3] = fexp2(s3[i+3] - mrun); r3 += s3[i+3];
        }
        #pragma unroll
        for (int kb = 0; kb < 2; ++kb) {
            #pragma unroll
            for (int c = 0; c < 2; ++c) {
                unsigned x0, x1, y0, y1;
                if (kb == 0) {
                    x0 = cvtpk(s2[8*c+0], s2[8*c+1]); x1 = cvtpk(s2[8*c+2], s2[8*c+3]);
                    y0 = cvtpk(s2[8*c+4], s2[8*c+5]); y1 = cvtpk(s2[8*c+6], s2[8*c+7]);
                } else {
                    x0 = cvtpk(s3[8*c+0], s3[8*c+1]); x1 = cvtpk(s3[8*c+2], s3[8*c+3]);
                    y0 = cvtpk(s3[8*c+4], s3[8*c+5]); y1 = cvtpk(s3[8*c+6], s3[8*c+7]);
                }
                asm volatile("v_permlane32_swap_b32 %0, %1" : "+v"(x0), "+v"(y0));
                asm volatile("v_permlane32_swap_b32 %0, %1" : "+v"(x1), "+v"(y1));
                union { unsigned u[4]; bf16x8 v; } U;
                U.u[0] = x0; U.u[1] = x1; U.u[2] = y0; U.u[3] = y1;
                pa[4 + kb * 2 + c] = U.v;
            }
        }
        lsumh += (r0 + r1) + (r2 + r3);

        // ---- O^T += V^T P^T : 32 MFMAs, 4 chains ----
        __builtin_amdgcn_s_setprio(1);
        #pragma unroll
        for (int db = 0; db < 4; ++db) {
            const int vrow = (db * 32 + q5) * 256 + ((hi * 16) ^ sw);
            #pragma unroll
            for (int ks = 0; ks < 8; ++ks) {
                bf16x8 vf = *(const bf16x8*)(smem + 32768 + (vrow ^ (ks << 5)));
                acc[db] = __builtin_amdgcn_mfma_f32_32x32x16_bf16(vf, pa[ks], acc[db], 0, 0, 0);
            }
        }
        __builtin_amdgcn_s_setprio(0);
        __builtin_amdgcn_sched_barrier(0);

        if (tt + 1 < NTILES) {
            __builtin_amdgcn_s_barrier();      // barC: all PV done -> Vbuf free
            STAGE_V(tt + 1);                   // hidden under next phase's QK
        }
    }

    // ---- epilogue: O^T -> O via LDS transpose, 2 rounds ----
    __syncthreads();
    const float lsum = lsumh + __shfl_xor(lsumh, 32);
    const float inv  = 1.0f / lsum;

    #pragma unroll
    for (int round = 0; round < 2; ++round) {
        if ((wv >> 1) == round) {
            const int eb = (wv & 1) * 16896;
            #pragma unroll
            for (int db = 0; db < 4; ++db) {
                #pragma unroll
                for (int c = 0; c < 4; ++c) {
                    f32x4 v;
                    v[0] = acc[db][4*c+0] * inv;
                    v[1] = acc[db][4*c+1] * inv;
                    v[2] = acc[db][4*c+2] * inv;
                    v[3] = acc[db][4*c+3] * inv;
                    *(f32x4*)(smem + eb + q5 * 528 + db * 128 + c * 32 + hi * 16) = v;
                }
            }
            #pragma unroll
            for (int i = 0; i < 16; ++i) {
                const int flat  = lane + i * 64;
                const int row   = flat >> 5;
                const int chunk = flat & 31;
                f32x4 v = *(const f32x4*)(smem + eb + row * 528 + chunk * 16);
                *(f32x4*)(O + base + (size_t)(q0 + wv * 32 + row) * DHEAD + chunk * 4) = v;
            }
        }
        __syncthreads();
    }
#undef STAGE_K
#undef STAGE_V
}

// ---------------- fallback (known-correct; used only if ws too small) ----------------
__global__ __launch_bounds__(NTHREADS) void attn_fwd_fallback(
    const float* __restrict__ Q, const float* __restrict__ K,
    const float* __restrict__ V, float* __restrict__ O)
{
    __shared__ ushort Ksh[64 * 136];
    __shared__ ushort Vsh[DHEAD * 72];
    __shared__ ushort Psh[4][16 * PSTR];

    const int t    = threadIdx.x;
    const int lane = t & 63;
    const int wv   = t >> 6;
    const int lq   = lane & 15;
    const int kh   = lane >> 4;

    const int bh = blockIdx.y;
    const int q0 = blockIdx.x * 64;
    const size_t base = (size_t)bh * SREF * DHEAD;

    const float scale = 0.08838834764831845f;
    bf16x8 qf[4];
    {
        const float* qrow = Q + base + (size_t)(q0 + wv * 16 + lq) * DHEAD;
        #pragma unroll
        for (int kk = 0; kk < 4; ++kk) {
            const int d0 = kk * 32 + kh * 8;
            float4 a = *(const float4*)(qrow + d0);
            float4 b = *(const float4*)(qrow + d0 + 4);
            bf16x8 f;
            f[0] = (short)f2bf(a.x * scale); f[1] = (short)f2bf(a.y * scale);
            f[2] = (short)f2bf(a.z * scale); f[3] = (short)f2bf(a.w * scale);
            f[4] = (short)f2bf(b.x * scale); f[5] = (short)f2bf(b.y * scale);
            f[6] = (short)f2bf(b.z * scale); f[7] = (short)f2bf(b.w * scale);
            qf[kk] = f;
        }
    }

    float mrun[4], lrun[4];
    f32x4 acc_o[8];
    #pragma unroll
    for (int r = 0; r < 4; ++r) { mrun[r] = -1e30f; lrun[r] = 0.0f; }
    #pragma unroll
    for (int db = 0; db < 8; ++db) acc_o[db] = (f32x4){0.f, 0.f, 0.f, 0.f};

    for (int kv0 = 0; kv0 < SREF; kv0 += 64) {
        __syncthreads();
        const float* kbase = K + base + (size_t)kv0 * DHEAD;
        #pragma unroll
        for (int i = 0; i < 8; ++i) {
            const int idx = t + i * NTHREADS;
            const int row = idx >> 5;
            const int c4  = idx & 31;
            float4 f = *(const float4*)(kbase + row * DHEAD + c4 * 4);
            ushort4 h;
            h.x = f2bf(f.x); h.y = f2bf(f.y); h.z = f2bf(f.z); h.w = f2bf(f.w);
            *(ushort4*)&Ksh[row * 136 + c4 * 4] = h;
        }
        const float* vbase = V + base + (size_t)kv0 * DHEAD;
        #pragma unroll
        for (int i = 0; i < 8; ++i) {
            const int key = (t & 31) + 32 * (i & 1);
            const int d4  = (t >> 5) + 8 * (i >> 1);
            float4 f = *(const float4*)(vbase + key * DHEAD + d4 * 4);
            Vsh[(d4 * 4 + 0) * 72 + key] = f2bf(f.x);
            Vsh[(d4 * 4 + 1) * 72 + key] = f2bf(f.y);
            Vsh[(d4 * 4 + 2) * 72 + key] = f2bf(f.z);
            Vsh[(d4 * 4 + 3) * 72 + key] = f2bf(f.w);
        }
        __syncthreads();

        f32x4 accs[4];
        #pragma unroll
        for (int nb = 0; nb < 4; ++nb) accs[nb] = (f32x4){0.f, 0.f, 0.f, 0.f};
        #pragma unroll
        for (int kk = 0; kk < 4; ++kk) {
            #pragma unroll
            for (int nb = 0; nb < 4; ++nb) {
                bf16x8 kf = *(const bf16x8*)&Ksh[(nb * 16 + lq) * 136 + kk * 32 + kh * 8];
                accs[nb] = __builtin_amdgcn_mfma_f32_16x16x32_bf16(qf[kk], kf, accs[nb], 0, 0, 0);
            }
        }

        float ps[4][4];
        #pragma unroll
        for (int r = 0; r < 4; ++r) {
            float v = fmaxf(fmaxf(accs[0][r], accs[1][r]), fmaxf(accs[2][r], accs[3][r]));
            #pragma unroll
            for (int mk = 1; mk < 16; mk <<= 1) v = fmaxf(v, __shfl_xor(v, mk));
            const float mnew  = fmaxf(mrun[r], v);
            const float alpha = __expf(mrun[r] - mnew);
            mrun[r] = mnew;
            float rs = 0.0f;
            #pragma unroll
            for (int nb = 0; nb < 4; ++nb) {
                const float p = __expf(accs[nb][r] - mnew);
                ps[nb][r] = p;
                rs += p;
            }
            #pragma unroll
            for (int mk = 1; mk < 16; mk <<= 1) rs += __shfl_xor(rs, mk);
            lrun[r] = lrun[r] * alpha + rs;
            #pragma unroll
            for (int db = 0; db < 8; ++db) acc_o[db][r] *= alpha;
        }

        #pragma unroll
        for (int nb = 0; nb < 4; ++nb)
            #pragma unroll
            for (int r = 0; r < 4; ++r)
                Psh[wv][(kh * 4 + r) * PSTR + nb * 16 + lq] = f2bf(ps[nb][r]);

        #pragma unroll
        for (int ks = 0; ks < 2; ++ks) {
            bf16x8 pa = *(const bf16x8*)&Psh[wv][lq * PSTR + ks * 32 + kh * 8];
            #pragma unroll
            for (int db = 0; db < 8; ++db) {
                bf16x8 vf = *(const bf16x8*)&Vsh[(db * 16 + lq) * 72 + ks * 32 + kh * 8];
                acc_o[db] = __builtin_amdgcn_mfma_f32_16x16x32_bf16(pa, vf, acc_o[db], 0, 0, 0);
            }
        }
    }

    #pragma unroll
    for (int r = 0; r < 4; ++r) {
        const float inv = 1.0f / lrun[r];
        float* orow = O + base + (size_t)(q0 + wv * 16 + kh * 4 + r) * DHEAD;
        #pragma unroll
        for (int db = 0; db < 8; ++db)
            orow[db * 16 + lq] = acc_o[db][r] * inv;
    }
}

extern "C" void kernel_launch(void* const* d_in, const int* in_sizes, int n_in,
                              void* d_out, int out_size, void* d_ws, size_t ws_size,
                              hipStream_t stream) {
    const float* Q = (const float*)d_in[0];
    const float* K = (const float*)d_in[1];
    const float* V = (const float*)d_in[2];
    float* O = (float*)d_out;
    const int BH = in_sizes[0] / (SREF * DHEAD);
    const size_t nel = (size_t)BH * SREF * DHEAD;

    if (ws_size >= 2 * nel * sizeof(ushort)) {
        ushort* Kb  = (ushort*)d_ws;
        ushort* VTb = Kb + nel;
        preconv_kernel<<<dim3(SREF / 64, BH), NTHREADS, 0, stream>>>(K, V, Kb, VTb);
        // T1: head on x (fastest) -> block%NXCD == head%NXCD -> per-head XCD affinity
        attn_fwd_kernel<<<dim3(BH, SREF / 128), NTHREADS, 0, stream>>>(Q, Kb, VTb, O);
    } else {
        attn_fwd_fallback<<<dim3(SREF / 64, BH), NTHREADS, 0, stream>>>(Q, K, V, O);
    }
}

// Round 9
// 98.588 us; speedup vs baseline: 1.0233x; 1.0007x over previous
//
#include <hip/hip_runtime.h>
#include <hip/hip_bf16.h>

#define SREF 2048
#define DHEAD 128
#define KVBLK 64
#define NTHREADS 256          /* preconv / fallback */
#define ATHREADS 512          /* main attention */
#define NT (SREF / KVBLK)     /* 32 tiles */
#define PSTR 72
#define QSCALE 0.12751743f    /* log2(e)/sqrt(128) */
#define THRLOG 8.0f           /* defer-max threshold, log2 domain */

typedef short bf16x8 __attribute__((ext_vector_type(8)));
typedef float f32x4 __attribute__((ext_vector_type(4)));
typedef float f32x16 __attribute__((ext_vector_type(16)));

typedef const __attribute__((address_space(1))) void* gas_t;
typedef __attribute__((address_space(3))) void* las_t;

__device__ __forceinline__ ushort f2bf(float x) {
    unsigned u = __builtin_bit_cast(unsigned, x);
    u += 0x7fffu + ((u >> 16) & 1u);
    return (ushort)(u >> 16);
}

__device__ __forceinline__ float fexp2(float x) {
#if __has_builtin(__builtin_amdgcn_exp2f)
    return __builtin_amdgcn_exp2f(x);
#else
    return exp2f(x);
#endif
}

__device__ __forceinline__ unsigned cvtpk(float lo, float hi) {
    unsigned r;
    asm("v_cvt_pk_bf16_f32 %0, %1, %2" : "=v"(r) : "v"(lo), "v"(hi));
    return r;
}

// ---------------- precompute: K -> bf16, V -> V^T bf16 (rows d, SREF stride) --------
__global__ __launch_bounds__(NTHREADS) void preconv_kernel(
    const float* __restrict__ K, const float* __restrict__ V,
    ushort* __restrict__ Kb, ushort* __restrict__ VTb)
{
    __shared__ ushort T[DHEAD * PSTR];
    const int t  = threadIdx.x;
    const int bh = blockIdx.y;
    const int s0 = blockIdx.x * 64;
    const size_t base = (size_t)bh * SREF * DHEAD;

    const float* kb = K + base + (size_t)s0 * DHEAD;
    ushort* kout = Kb + base + (size_t)s0 * DHEAD;
    #pragma unroll
    for (int i = 0; i < 8; ++i) {
        int idx = t + i * NTHREADS;
        float4 f = *(const float4*)(kb + idx * 4);
        ushort4 h; h.x = f2bf(f.x); h.y = f2bf(f.y); h.z = f2bf(f.z); h.w = f2bf(f.w);
        *(ushort4*)(kout + idx * 4) = h;
    }

    const float* vb = V + base + (size_t)s0 * DHEAD;
    #pragma unroll
    for (int i = 0; i < 8; ++i) {
        const int key = (t & 31) + 32 * (i & 1);
        const int d4  = (t >> 5) + 8 * (i >> 1);
        float4 f = *(const float4*)(vb + key * DHEAD + d4 * 4);
        T[(d4 * 4 + 0) * PSTR + key] = f2bf(f.x);
        T[(d4 * 4 + 1) * PSTR + key] = f2bf(f.y);
        T[(d4 * 4 + 2) * PSTR + key] = f2bf(f.z);
        T[(d4 * 4 + 3) * PSTR + key] = f2bf(f.w);
    }
    __syncthreads();

    ushort* vt = VTb + (size_t)bh * DHEAD * SREF + s0;
    #pragma unroll
    for (int i = 0; i < 4; ++i) {
        int idx = t + i * NTHREADS;
        int d = idx >> 3;
        int c = (idx & 7) * 8;
        bf16x8 v = *(const bf16x8*)&T[d * PSTR + c];
        *(bf16x8*)(vt + (size_t)d * SREF + c) = v;
    }
}

// softmax for one KVBLK=64 tile: scores (s0,s1) -> pa frags; updates mrun/lsumh/acc
__device__ __forceinline__ void softmax_step(
    f32x16& s0, f32x16& s1, float& mrun, float& lsumh,
    f32x16* acc, bf16x8* pa)
{
    float m0[8];
    #pragma unroll
    for (int i = 0; i < 8; ++i)
        m0[i] = fmaxf(fmaxf(s0[i], s0[i + 8]), fmaxf(s1[i], s1[i + 8]));
    float pmax = fmaxf(fmaxf(fmaxf(m0[0], m0[1]), fmaxf(m0[2], m0[3])),
                       fmaxf(fmaxf(m0[4], m0[5]), fmaxf(m0[6], m0[7])));
    pmax = fmaxf(pmax, __shfl_xor(pmax, 32));

    if (!__all(pmax <= mrun + THRLOG)) {        // defer-max (T13)
        const float mnew  = fmaxf(mrun, pmax);
        const float alpha = fexp2(mrun - mnew);
        mrun = mnew;
        lsumh *= alpha;
        #pragma unroll
        for (int db = 0; db < 4; ++db)
            #pragma unroll
            for (int i = 0; i < 16; ++i) acc[db][i] *= alpha;
    }

    float r0 = 0.f, r1 = 0.f, r2 = 0.f, r3 = 0.f;
    #pragma unroll
    for (int i = 0; i < 16; i += 4) {
        s0[i]   = fexp2(s0[i]   - mrun); r0 += s0[i];
        s0[i+1] = fexp2(s0[i+1] - mrun); r1 += s0[i+1];
        s0[i+2] = fexp2(s0[i+2] - mrun); r2 += s0[i+2];
        s0[i+3] = fexp2(s0[i+3] - mrun); r3 += s0[i+3];
    }
    #pragma unroll
    for (int i = 0; i < 16; i += 4) {
        s1[i]   = fexp2(s1[i]   - mrun); r0 += s1[i];
        s1[i+1] = fexp2(s1[i+1] - mrun); r1 += s1[i+1];
        s1[i+2] = fexp2(s1[i+2] - mrun); r2 += s1[i+2];
        s1[i+3] = fexp2(s1[i+3] - mrun); r3 += s1[i+3];
    }
    lsumh += (r0 + r1) + (r2 + r3);

    // P -> B-side bf16 frags in-register (T12)
    #pragma unroll
    for (int kb = 0; kb < 2; ++kb) {
        #pragma unroll
        for (int c = 0; c < 2; ++c) {
            unsigned x0, x1, y0, y1;
            if (kb == 0) {
                x0 = cvtpk(s0[8*c+0], s0[8*c+1]); x1 = cvtpk(s0[8*c+2], s0[8*c+3]);
                y0 = cvtpk(s0[8*c+4], s0[8*c+5]); y1 = cvtpk(s0[8*c+6], s0[8*c+7]);
            } else {
                x0 = cvtpk(s1[8*c+0], s1[8*c+1]); x1 = cvtpk(s1[8*c+2], s1[8*c+3]);
                y0 = cvtpk(s1[8*c+4], s1[8*c+5]); y1 = cvtpk(s1[8*c+6], s1[8*c+7]);
            }
            asm volatile("v_permlane32_swap_b32 %0, %1" : "+v"(x0), "+v"(y0));
            asm volatile("v_permlane32_swap_b32 %0, %1" : "+v"(x1), "+v"(y1));
            union { unsigned u[4]; bf16x8 v; } U;
            U.u[0] = x0; U.u[1] = x1; U.u[2] = y0; U.u[3] = y1;
            pa[kb * 2 + c] = U.v;
        }
    }
}

// ---------------- main attention: 8-wave ping-pong, 32x32 MFMA, KVBLK=64 --------------
// Block = 512 thr = 8 waves; wave w -> SIMD w%4; group g = w>>2. Every SIMD hosts one
// G0 + one G1 wave. Two regions per tile (block-wide barriers as rendezvous):
//   A(t): stage K(t+1),V(t);  G0: PV(t-1)+QK(t) [MFMA] | G1: SM(t-1) [VALU]
//   B(t):                     G0: SM(t)  [VALU]        | G1: PV(t-1)+QK(t) [MFMA]
//         vmcnt(0) (drains own A(t) loads, ~1 region old), barrier.
// LDS 64KB: Kbuf[b]@b*16384 ([64 keys][256B]); Vbuf[b]@32768+b*16384
//   ([64 r][256B] = {d=r | d=r+64} halves). 4-bit both-sides XOR swizzle (R7: 0 conflicts).
__global__ __launch_bounds__(ATHREADS, 2) void attn_fwd_kernel(
    const float* __restrict__ Q, const ushort* __restrict__ Kb,
    const ushort* __restrict__ VTb, float* __restrict__ O)
{
    __shared__ __align__(16) char smem[65536];

    const int t    = threadIdx.x;
    const int lane = t & 63;
    const int wv   = t >> 6;          // 0..7
    const int g    = wv >> 2;         // group: 0 = waves 0-3, 1 = waves 4-7
    const int hi   = lane >> 5;
    const int q5   = lane & 31;
    const int sw   = (q5 & 15) << 4;

    const int bh = blockIdx.x;        // head fastest -> XCD affinity (T1, R8-proven)
    const int q0 = blockIdx.y * 256;
    const size_t base = (size_t)bh * SREF * DHEAD;

    // ---- Q B-fragments (log2-scaled), rows q0 + wv*32 + q5 ----
    bf16x8 qf[8];
    {
        const float* qrow = Q + base + (size_t)(q0 + wv * 32 + q5) * DHEAD;
        #pragma unroll
        for (int dk = 0; dk < 8; ++dk) {
            const int d0 = dk * 16 + hi * 8;
            float4 a = *(const float4*)(qrow + d0);
            float4 b = *(const float4*)(qrow + d0 + 4);
            bf16x8 f;
            f[0] = (short)f2bf(a.x * QSCALE); f[1] = (short)f2bf(a.y * QSCALE);
            f[2] = (short)f2bf(a.z * QSCALE); f[3] = (short)f2bf(a.w * QSCALE);
            f[4] = (short)f2bf(b.x * QSCALE); f[5] = (short)f2bf(b.y * QSCALE);
            f[6] = (short)f2bf(b.z * QSCALE); f[7] = (short)f2bf(b.w * QSCALE);
            qf[dk] = f;
        }
    }

    const char* ksrcb = (const char*)(Kb + base);
    const char* vsrcb = (const char*)(VTb + (size_t)bh * DHEAD * SREF);

    const int kread = q5 * 256 + ((hi * 16) ^ sw);   // K: row=key, chain c adds c*8192
    const int vread = q5 * 256 + ((hi * 16) ^ sw);   // V: row r, db adds (db&1)*8192,
                                                     //    XOR (ks<<5) ^ ((db>>1)<<7)

// stage K tile tt (16KB contiguous) into Kbuf[tt&1]; 2 x 16B per thread
#define STAGE_K(tt) do {                                                        \
    const char* kt_ = ksrcb + (size_t)(tt) * 16384;                             \
    _Pragma("unroll")                                                           \
    for (int i_ = 0; i_ < 2; ++i_) {                                            \
        int L_ = t * 16 + i_ * 8192;                                            \
        int r_ = L_ >> 8;                                                       \
        __builtin_amdgcn_global_load_lds(                                       \
            (gas_t)(const void*)(kt_ + (L_ ^ ((r_ & 15) << 4))),                \
            (las_t)(void*)(smem + ((tt) & 1) * 16384 + L_), 16, 0, 0);          \
    }                                                                           \
} while (0)

// stage V tile tt into Vbuf[tt&1]; LDS row r holds {d=r (128B) | d=r+64 (128B)}
#define STAGE_V(tt) do {                                                        \
    const char* vt_ = vsrcb + (size_t)(tt) * 128;                               \
    _Pragma("unroll")                                                           \
    for (int i_ = 0; i_ < 2; ++i_) {                                            \
        int L_ = t * 16 + i_ * 8192;                                            \
        int r_ = L_ >> 8;                                                       \
        int offp_ = (L_ & 255) ^ ((r_ & 15) << 4);                              \
        int d_ = r_ + 64 * (offp_ >> 7);                                        \
        __builtin_amdgcn_global_load_lds(                                       \
            (gas_t)(const void*)(vt_ + (size_t)d_ * (SREF * 2) + (offp_ & 127)),\
            (las_t)(void*)(smem + 32768 + ((tt) & 1) * 16384 + L_), 16, 0, 0);  \
    }                                                                           \
} while (0)

// QK(t): S^T = K Q^T, 16 MFMAs, 2 chains (keys 0-31 -> s0, 32-63 -> s1)
#define QK(tt) do {                                                             \
    const int kO_ = ((tt) & 1) * 16384;                                         \
    _Pragma("unroll")                                                           \
    for (int i_ = 0; i_ < 16; ++i_) { s0[i_] = 0.f; s1[i_] = 0.f; }             \
    __builtin_amdgcn_s_setprio(1);                                              \
    _Pragma("unroll")                                                           \
    for (int dk_ = 0; dk_ < 8; ++dk_) {                                         \
        const int off_ = kread ^ (dk_ << 5);                                    \
        bf16x8 kf0 = *(const bf16x8*)(smem + kO_ + off_);                       \
        s0 = __builtin_amdgcn_mfma_f32_32x32x16_bf16(kf0, qf[dk_], s0, 0, 0, 0);\
        bf16x8 kf1 = *(const bf16x8*)(smem + kO_ + 8192 + off_);                \
        s1 = __builtin_amdgcn_mfma_f32_32x32x16_bf16(kf1, qf[dk_], s1, 0, 0, 0);\
    }                                                                           \
    __builtin_amdgcn_s_setprio(0);                                              \
} while (0)

// PV(t): O^T += V^T P^T, 16 MFMAs; acc[db] covers d = db*32 + crow
#define PV(tt) do {                                                             \
    const int vO_ = 32768 + ((tt) & 1) * 16384;                                 \
    __builtin_amdgcn_s_setprio(1);                                              \
    _Pragma("unroll")                                                           \
    for (int db_ = 0; db_ < 4; ++db_) {                                         \
        const int vb_ = vread + (db_ & 1) * 8192;                               \
        _Pragma("unroll")                                                       \
        for (int ks_ = 0; ks_ < 4; ++ks_) {                                     \
            bf16x8 vf = *(const bf16x8*)(smem + vO_ +                           \
                (vb_ ^ (ks_ << 5) ^ ((db_ >> 1) << 7)));                        \
            acc[db_] = __builtin_amdgcn_mfma_f32_32x32x16_bf16(vf, pa[ks_], acc[db_], 0, 0, 0); \
        }                                                                       \
    }                                                                           \
    __builtin_amdgcn_s_setprio(0);                                              \
} while (0)

#define BAR() do { __builtin_amdgcn_s_barrier(); __builtin_amdgcn_sched_barrier(0); } while (0)

    float mrun = -1e30f, lsumh = 0.0f;
    f32x16 acc[4];
    #pragma unroll
    for (int db = 0; db < 4; ++db)
        #pragma unroll
        for (int i = 0; i < 16; ++i) acc[db][i] = 0.0f;

    f32x16 s0, s1;
    bf16x8 pa[4];

    // ---- prologue: K(0) ready ----
    STAGE_K(0);
    asm volatile("s_waitcnt vmcnt(0)" ::: "memory");
    BAR();

    // ---- t = 0 (peeled: no PV(-1)/SM(-1)) ----
    STAGE_K(1);
    STAGE_V(0);
    if (g == 0) { QK(0); }
    BAR();
    if (g == 0) { softmax_step(s0, s1, mrun, lsumh, acc, pa); }
    else        { QK(0); }
    asm volatile("s_waitcnt vmcnt(0)" ::: "memory");
    BAR();

    // ---- steady state t = 1..NT-1 ----
    #pragma unroll 1
    for (int tt = 1; tt < NT; ++tt) {
        if (tt + 1 < NT) STAGE_K(tt + 1);
        STAGE_V(tt);
        if (g == 0) { PV(tt - 1); QK(tt); }
        else        { softmax_step(s0, s1, mrun, lsumh, acc, pa); }   // SM(tt-1)
        BAR();
        if (g == 0) { softmax_step(s0, s1, mrun, lsumh, acc, pa); }   // SM(tt)
        else        { PV(tt - 1); QK(tt); }
        asm volatile("s_waitcnt vmcnt(0)" ::: "memory");
        BAR();
    }

    // ---- tail ----
    if (g == 0) { PV(NT - 1); }
    else        { softmax_step(s0, s1, mrun, lsumh, acc, pa); }       // SM(NT-1)
    BAR();
    if (g == 1) { PV(NT - 1); }

    // ---- epilogue: O^T -> O via LDS transpose, 3 rounds of <=3 waves ----
    __syncthreads();
    const float lsum = lsumh + __shfl_xor(lsumh, 32);
    const float inv  = 1.0f / lsum;

    #pragma unroll
    for (int round = 0; round < 3; ++round) {
        if (wv / 3 == round) {
            const int eb = (wv % 3) * 16896;
            #pragma unroll
            for (int db = 0; db < 4; ++db) {
                #pragma unroll
                for (int c = 0; c < 4; ++c) {
                    f32x4 v;
                    v[0] = acc[db][4*c+0] * inv;
                    v[1] = acc[db][4*c+1] * inv;
                    v[2] = acc[db][4*c+2] * inv;
                    v[3] = acc[db][4*c+3] * inv;
                    // d = 32*db + 8*c + 4*hi + e
                    *(f32x4*)(smem + eb + q5 * 528 + db * 128 + c * 32 + hi * 16) = v;
                }
            }
            #pragma unroll
            for (int i = 0; i < 16; ++i) {
                const int flat  = lane + i * 64;
                const int row   = flat >> 5;
                const int chunk = flat & 31;
                f32x4 v = *(const f32x4*)(smem + eb + row * 528 + chunk * 16);
                *(f32x4*)(O + base + (size_t)(q0 + wv * 32 + row) * DHEAD + chunk * 4) = v;
            }
        }
        __syncthreads();
    }
#undef STAGE_K
#undef STAGE_V
#undef QK
#undef PV
#undef BAR
}

// ---------------- fallback (known-correct; used only if ws too small) ----------------
__global__ __launch_bounds__(NTHREADS) void attn_fwd_fallback(
    const float* __restrict__ Q, const float* __restrict__ K,
    const float* __restrict__ V, float* __restrict__ O)
{
    __shared__ ushort Ksh[64 * 136];
    __shared__ ushort Vsh[DHEAD * 72];
    __shared__ ushort Psh[4][16 * PSTR];

    const int t    = threadIdx.x;
    const int lane = t & 63;
    const int wv   = t >> 6;
    const int lq   = lane & 15;
    const int kh   = lane >> 4;

    const int bh = blockIdx.y;
    const int q0 = blockIdx.x * 64;
    const size_t base = (size_t)bh * SREF * DHEAD;

    const float scale = 0.08838834764831845f;
    bf16x8 qf[4];
    {
        const float* qrow = Q + base + (size_t)(q0 + wv * 16 + lq) * DHEAD;
        #pragma unroll
        for (int kk = 0; kk < 4; ++kk) {
            const int d0 = kk * 32 + kh * 8;
            float4 a = *(const float4*)(qrow + d0);
            float4 b = *(const float4*)(qrow + d0 + 4);
            bf16x8 f;
            f[0] = (short)f2bf(a.x * scale); f[1] = (short)f2bf(a.y * scale);
            f[2] = (short)f2bf(a.z * scale); f[3] = (short)f2bf(a.w * scale);
            f[4] = (short)f2bf(b.x * scale); f[5] = (short)f2bf(b.y * scale);
            f[6] = (short)f2bf(b.z * scale); f[7] = (short)f2bf(b.w * scale);
            qf[kk] = f;
        }
    }

    float mrun[4], lrun[4];
    f32x4 acc_o[8];
    #pragma unroll
    for (int r = 0; r < 4; ++r) { mrun[r] = -1e30f; lrun[r] = 0.0f; }
    #pragma unroll
    for (int db = 0; db < 8; ++db) acc_o[db] = (f32x4){0.f, 0.f, 0.f, 0.f};

    for (int kv0 = 0; kv0 < SREF; kv0 += 64) {
        __syncthreads();
        const float* kbase = K + base + (size_t)kv0 * DHEAD;
        #pragma unroll
        for (int i = 0; i < 8; ++i) {
            const int idx = t + i * NTHREADS;
            const int row = idx >> 5;
            const int c4  = idx & 31;
            float4 f = *(const float4*)(kbase + row * DHEAD + c4 * 4);
            ushort4 h;
            h.x = f2bf(f.x); h.y = f2bf(f.y); h.z = f2bf(f.z); h.w = f2bf(f.w);
            *(ushort4*)&Ksh[row * 136 + c4 * 4] = h;
        }
        const float* vbase = V + base + (size_t)kv0 * DHEAD;
        #pragma unroll
        for (int i = 0; i < 8; ++i) {
            const int key = (t & 31) + 32 * (i & 1);
            const int d4  = (t >> 5) + 8 * (i >> 1);
            float4 f = *(const float4*)(vbase + key * DHEAD + d4 * 4);
            Vsh[(d4 * 4 + 0) * 72 + key] = f2bf(f.x);
            Vsh[(d4 * 4 + 1) * 72 + key] = f2bf(f.y);
            Vsh[(d4 * 4 + 2) * 72 + key] = f2bf(f.z);
            Vsh[(d4 * 4 + 3) * 72 + key] = f2bf(f.w);
        }
        __syncthreads();

        f32x4 accs[4];
        #pragma unroll
        for (int nb = 0; nb < 4; ++nb) accs[nb] = (f32x4){0.f, 0.f, 0.f, 0.f};
        #pragma unroll
        for (int kk = 0; kk < 4; ++kk) {
            #pragma unroll
            for (int nb = 0; nb < 4; ++nb) {
                bf16x8 kf = *(const bf16x8*)&Ksh[(nb * 16 + lq) * 136 + kk * 32 + kh * 8];
                accs[nb] = __builtin_amdgcn_mfma_f32_16x16x32_bf16(qf[kk], kf, accs[nb], 0, 0, 0);
            }
        }

        float ps[4][4];
        #pragma unroll
        for (int r = 0; r < 4; ++r) {
            float v = fmaxf(fmaxf(accs[0][r], accs[1][r]), fmaxf(accs[2][r], accs[3][r]));
            #pragma unroll
            for (int mk = 1; mk < 16; mk <<= 1) v = fmaxf(v, __shfl_xor(v, mk));
            const float mnew  = fmaxf(mrun[r], v);
            const float alpha = __expf(mrun[r] - mnew);
            mrun[r] = mnew;
            float rs = 0.0f;
            #pragma unroll
            for (int nb = 0; nb < 4; ++nb) {
                const float p = __expf(accs[nb][r] - mnew);
                ps[nb][r] = p;
                rs += p;
            }
            #pragma unroll
            for (int mk = 1; mk < 16; mk <<= 1) rs += __shfl_xor(rs, mk);
            lrun[r] = lrun[r] * alpha + rs;
            #pragma unroll
            for (int db = 0; db < 8; ++db) acc_o[db][r] *= alpha;
        }

        #pragma unroll
        for (int nb = 0; nb < 4; ++nb)
            #pragma unroll
            for (int r = 0; r < 4; ++r)
                Psh[wv][(kh * 4 + r) * PSTR + nb * 16 + lq] = f2bf(ps[nb][r]);

        #pragma unroll
        for (int ks = 0; ks < 2; ++ks) {
            bf16x8 pa = *(const bf16x8*)&Psh[wv][lq * PSTR + ks * 32 + kh * 8];
            #pragma unroll
            for (int db = 0; db < 8; ++db) {
                bf16x8 vf = *(const bf16x8*)&Vsh[(db * 16 + lq) * 72 + ks * 32 + kh * 8];
                acc_o[db] = __builtin_amdgcn_mfma_f32_16x16x32_bf16(pa, vf, acc_o[db], 0, 0, 0);
            }
        }
    }

    #pragma unroll
    for (int r = 0; r < 4; ++r) {
        const float inv = 1.0f / lrun[r];
        float* orow = O + base + (size_t)(q0 + wv * 16 + kh * 4 + r) * DHEAD;
        #pragma unroll
        for (int db = 0; db < 8; ++db)
            orow[db * 16 + lq] = acc_o[db][r] * inv;
    }
}

extern "C" void kernel_launch(void* const* d_in, const int* in_sizes, int n_in,
                              void* d_out, int out_size, void* d_ws, size_t ws_size,
                              hipStream_t stream) {
    const float* Q = (const float*)d_in[0];
    const float* K = (const float*)d_in[1];
    const float* V = (const float*)d_in[2];
    float* O = (float*)d_out;
    const int BH = in_sizes[0] / (SREF * DHEAD);
    const size_t nel = (size_t)BH * SREF * DHEAD;

    if (ws_size >= 2 * nel * sizeof(ushort)) {
        ushort* Kb  = (ushort*)d_ws;
        ushort* VTb = Kb + nel;
        preconv_kernel<<<dim3(SREF / 64, BH), NTHREADS, 0, stream>>>(K, V, Kb, VTb);
        // head on x -> block%8 == head%8 -> per-head XCD affinity (T1, R8-proven)
        attn_fwd_kernel<<<dim3(BH, SREF / 256), ATHREADS, 0, stream>>>(Q, Kb, VTb, O);
    } else {
        attn_fwd_fallback<<<dim3(SREF / 64, BH), NTHREADS, 0, stream>>>(Q, K, V, O);
    }
}